// Round 1
// baseline (46694.986 us; speedup 1.0000x reference)
//
#include <hip/hip_runtime.h>
#include <hip/hip_bf16.h>
#include <math.h>

#define KDIM   2048
#define TSTEPS 1024
#define NNZ    4096
#define BEAMS  16
#define CAND_CAP 2048

// posterior in the reference's exact association order:
// ((lps + d) + ((v0 - m0) - L0)) + ((v1 - m1) - L1)
__device__ __forceinline__ float post_val(float lpsb, float d,
                                          float v0, float mm0, float ll0,
                                          float v1, float mm1, float ll1) {
    return ((lpsb + d) + ((v0 - mm0) - ll0)) + ((v1 - mm1) - ll1);
}

// ---------- kernel 1: scaled tables = prior / 0.7 (true IEEE divide) ----------
__global__ void scale_kernel(const float* __restrict__ p0,
                             const float* __restrict__ p1,
                             float* __restrict__ sc) {
    const int NF4 = (KDIM * KDIM) / 4;   // 1048576 float4 per table
    int i = blockIdx.x * blockDim.x + threadIdx.x;   // 0 .. 2*NF4-1
    float4 v;
    if (i < NF4) v = ((const float4*)p0)[i];
    else         v = ((const float4*)p1)[i - NF4];
    v.x = v.x / 0.7f; v.y = v.y / 0.7f; v.z = v.z / 0.7f; v.w = v.w / 0.7f;
    ((float4*)sc)[i] = v;
}

// ---------- kernel 2: per-row max + log-sum-exp of the scaled rows ----------
__global__ void rowstat_kernel(const float* __restrict__ sc,
                               float* __restrict__ mArr,
                               float* __restrict__ lArr) {
    __shared__ float red[4];
    __shared__ float bm;
    const int r = blockIdx.x;                    // 0..4095 (both tables)
    const float* row = sc + (size_t)r * KDIM;
    const int tid = threadIdx.x;                 // 256 threads
    const int lane = tid & 63, wv = tid >> 6;

    float4 a = ((const float4*)row)[tid];
    float4 b = ((const float4*)row)[tid + 256];
    float m = fmaxf(fmaxf(fmaxf(a.x, a.y), fmaxf(a.z, a.w)),
                    fmaxf(fmaxf(b.x, b.y), fmaxf(b.z, b.w)));
    for (int s = 32; s; s >>= 1) m = fmaxf(m, __shfl_xor(m, s));
    if (lane == 0) red[wv] = m;
    __syncthreads();
    if (tid == 0) bm = fmaxf(fmaxf(red[0], red[1]), fmaxf(red[2], red[3]));
    __syncthreads();
    const float mm = bm;

    float s = expf(a.x - mm);
    s += expf(a.y - mm); s += expf(a.z - mm); s += expf(a.w - mm);
    s += expf(b.x - mm); s += expf(b.y - mm); s += expf(b.z - mm); s += expf(b.w - mm);
    for (int sh = 32; sh; sh >>= 1) s += __shfl_xor(s, sh);
    __syncthreads();                 // red[] reuse hazard
    if (lane == 0) red[wv] = s;
    __syncthreads();
    if (tid == 0) {
        float S = ((red[0] + red[1]) + red[2]) + red[3];
        mArr[r] = mm;
        lArr[r] = logf(S);
    }
}

// ---------- kernel 3: persistent single-workgroup beam search ----------
__global__ __launch_bounds__(1024) void beam_kernel(
    const float* __restrict__ sc,        // [2*2048][2048] scaled tables
    const float* __restrict__ mArr,      // [4096]
    const float* __restrict__ lArr,      // [4096]
    const float* __restrict__ ll_data,   // [1024][4096]
    const int*   __restrict__ ll_coords, // [1024][2][4096]
    const int*   __restrict__ x0i,
    const int*   __restrict__ x1i,
    float* __restrict__ out)
{
    __shared__ float buf[2][2][KDIM];           // double-buffered beam rows, 32KB
    __shared__ int   sx0[BEAMS], sx1[BEAMS];
    __shared__ float slps[BEAMS];
    __shared__ float smm0[BEAMS], sll0[BEAMS], smm1[BEAMS], sll1[BEAMS];
    __shared__ float wave16[16];
    __shared__ int   scnt;
    __shared__ float cand_v[CAND_CAP];
    __shared__ int   cand_i[CAND_CAP];
    __shared__ float res_v[BEAMS];
    __shared__ int   res_i[BEAMS];

    const int tid  = threadIdx.x;
    const int lane = tid & 63;
    const int wv   = tid >> 6;
    const int srow = tid >> 9;                  // which of the 2 rows this thread stages
    const int scol = (tid * 4) & (KDIM - 1);    // 4-float chunk within the row
    const float* sc1 = sc + (size_t)KDIM * KDIM;

    if (tid < BEAMS) { sx0[tid] = x0i[tid]; sx1[tid] = x1i[tid]; slps[tid] = 0.0f; }
    __syncthreads();

#pragma unroll 1
    for (int t = 0; t < TSTEPS; ++t) {
        // per-beam normalizer stats for this step's active rows
        if (tid < BEAMS) {
            int r0 = sx0[tid], r1 = sx1[tid];
            smm0[tid] = mArr[r0];        sll0[tid] = lArr[r0];
            smm1[tid] = mArr[KDIM + r1]; sll1[tid] = lArr[KDIM + r1];
        }
        if (tid == 0) scnt = 0;

        // stream this step's data / coords (held in registers all step)
        const float* dp = ll_data + (size_t)t * NNZ;
        const int*   cp = ll_coords + (size_t)t * 2 * NNZ;
        float4 d4  = ((const float4*)dp)[tid];
        int4   c04 = ((const int4*)cp)[tid];
        int4   c14 = ((const int4*)(cp + NNZ))[tid];

        // stage beam 0 into phase 0
        {
            int rr = (srow == 0) ? sx0[0] : sx1[0];
            const float* base = (srow == 0) ? sc : sc1;
            float4 st = *(const float4*)(base + (size_t)rr * KDIM + scol);
            *(float4*)&buf[0][srow][scol] = st;
        }
        __syncthreads();

        float best = -INFINITY;
#pragma unroll 1
        for (int b = 0; b < BEAMS; ++b) {
            float4 stn;
            if (b < BEAMS - 1) {            // issue next beam's row load early (T14)
                int rr = (srow == 0) ? sx0[b + 1] : sx1[b + 1];
                const float* base = (srow == 0) ? sc : sc1;
                stn = *(const float4*)(base + (size_t)rr * KDIM + scol);
            }
            const int ph = b & 1;
            const float* r0 = buf[ph][0];
            const float* r1 = buf[ph][1];
            const float lpsb = slps[b];
            const float q0 = smm0[b], g0 = sll0[b];
            const float q1 = smm1[b], g1 = sll1[b];
            float p;
            p = post_val(lpsb, d4.x, r0[c04.x], q0, g0, r1[c14.x], q1, g1); best = fmaxf(best, p);
            p = post_val(lpsb, d4.y, r0[c04.y], q0, g0, r1[c14.y], q1, g1); best = fmaxf(best, p);
            p = post_val(lpsb, d4.z, r0[c04.z], q0, g0, r1[c14.z], q1, g1); best = fmaxf(best, p);
            p = post_val(lpsb, d4.w, r0[c04.w], q0, g0, r1[c14.w], q1, g1); best = fmaxf(best, p);
            if (b < BEAMS - 1) {
                *(float4*)&buf[ph ^ 1][srow][scol] = stn;   // write-late
            }
            __syncthreads();
        }

        // tau = max over waves of (16th-largest lane-best within the wave).
        // Guarantees >=16 posterior values >= tau, and tau <= true 16th largest.
        {
            float cur = best;
            float wth = -INFINITY;
#pragma unroll 1
            for (int k = 0; k < 16; ++k) {
                float wm = cur;
                for (int s = 32; s; s >>= 1) wm = fmaxf(wm, __shfl_xor(wm, s));
                wth = wm;
                cur = (cur == wm) ? -INFINITY : cur;
            }
            if (lane == 0) wave16[wv] = wth;
        }
        __syncthreads();
        float tau = wave16[0];
#pragma unroll
        for (int k = 1; k < 16; ++k) tau = fmaxf(tau, wave16[k]);

        // collect: qualifying threads recompute their 64 values from the global
        // scaled tables (bit-identical) and push all values >= tau
        if (best >= tau) {
#pragma unroll 1
            for (int b = 0; b < BEAMS; ++b) {
                const float* r0 = sc  + (size_t)sx0[b] * KDIM;
                const float* r1 = sc1 + (size_t)sx1[b] * KDIM;
                const float lpsb = slps[b];
                const float q0 = smm0[b], g0 = sll0[b];
                const float q1 = smm1[b], g1 = sll1[b];
                const int nb = b << 12;
                float p;
                p = post_val(lpsb, d4.x, r0[c04.x], q0, g0, r1[c14.x], q1, g1);
                if (p >= tau) { int pos = atomicAdd(&scnt, 1); if (pos < CAND_CAP) { cand_v[pos] = p; cand_i[pos] = nb + tid * 4 + 0; } }
                p = post_val(lpsb, d4.y, r0[c04.y], q0, g0, r1[c14.y], q1, g1);
                if (p >= tau) { int pos = atomicAdd(&scnt, 1); if (pos < CAND_CAP) { cand_v[pos] = p; cand_i[pos] = nb + tid * 4 + 1; } }
                p = post_val(lpsb, d4.z, r0[c04.z], q0, g0, r1[c14.z], q1, g1);
                if (p >= tau) { int pos = atomicAdd(&scnt, 1); if (pos < CAND_CAP) { cand_v[pos] = p; cand_i[pos] = nb + tid * 4 + 2; } }
                p = post_val(lpsb, d4.w, r0[c04.w], q0, g0, r1[c14.w], q1, g1);
                if (p >= tau) { int pos = atomicAdd(&scnt, 1); if (pos < CAND_CAP) { cand_v[pos] = p; cand_i[pos] = nb + tid * 4 + 3; } }
            }
        }
        __syncthreads();

        // wave 0: extract top-16 with jax tie-break (value desc, flat idx asc)
        if (wv == 0) {
            int C = scnt; if (C > CAND_CAP) C = CAND_CAP;
#pragma unroll 1
            for (int rk = 0; rk < BEAMS; ++rk) {
                float bv = -INFINITY; int bi = 0x7FFFFFFF; int bj = -1;
                for (int j = lane; j < C; j += 64) {
                    float v = cand_v[j]; int ii = cand_i[j];
                    if (v > bv || (v == bv && ii < bi)) { bv = v; bi = ii; bj = j; }
                }
                for (int s = 32; s; s >>= 1) {
                    float ov = __shfl_xor(bv, s);
                    int   oi = __shfl_xor(bi, s);
                    int   oj = __shfl_xor(bj, s);
                    if (ov > bv || (ov == bv && oi < bi)) { bv = ov; bi = oi; bj = oj; }
                }
                if (lane == 0) { res_v[rk] = bv; res_i[rk] = bi; cand_v[bj] = -INFINITY; }
            }
            // state update + outputs
            if (lane < BEAMS) {
                float v = res_v[lane]; int idx = res_i[lane];
                int n = idx & (NNZ - 1);
                int tok0 = cp[n];
                int tok1 = cp[NNZ + n];
                sx0[lane] = tok0; sx1[lane] = tok1; slps[lane] = v;
                out[BEAMS + (size_t)t * BEAMS + lane] = (float)tok0;
                out[BEAMS + (size_t)TSTEPS * BEAMS + (size_t)t * BEAMS + lane] = (float)tok1;
                if (t == TSTEPS - 1) out[lane] = v;
            }
        }
        __syncthreads();
    }
}

extern "C" void kernel_launch(void* const* d_in, const int* in_sizes, int n_in,
                              void* d_out, int out_size, void* d_ws, size_t ws_size,
                              hipStream_t stream) {
    const float* p0        = (const float*)d_in[0];
    const float* p1        = (const float*)d_in[1];
    const float* ll_data   = (const float*)d_in[2];
    const int*   ll_coords = (const int*)d_in[3];
    const int*   x0i       = (const int*)d_in[4];
    const int*   x1i       = (const int*)d_in[5];
    float* outp = (float*)d_out;

    float* sc   = (float*)d_ws;                      // 2*2048*2048 floats (32MB)
    float* mArr = sc + (size_t)2 * KDIM * KDIM;      // 4096 floats
    float* lArr = mArr + 2 * KDIM;                   // 4096 floats

    scale_kernel<<<(2 * KDIM * KDIM / 4) / 256, 256, 0, stream>>>(p0, p1, sc);
    rowstat_kernel<<<2 * KDIM, 256, 0, stream>>>(sc, mArr, lArr);
    beam_kernel<<<1, 1024, 0, stream>>>(sc, mArr, lArr, ll_data, ll_coords, x0i, x1i, outp);
}

// Round 2
// 26379.288 us; speedup vs baseline: 1.7701x; 1.7701x over previous
//
#include <hip/hip_runtime.h>
#include <hip/hip_bf16.h>
#include <math.h>

#define KDIM   2048
#define TSTEPS 1024
#define NNZ    4096
#define BEAMS  16
#define NWG    64               // 4 workgroups per beam, one wave-width of lists
#define WPB    (NWG / BEAMS)    // 4
#define CHUNK  (NNZ / WPB)      // 1024 evals per WG
#define LCAP   1024             // LDS candidate list capacity (cannot overflow)

// posterior in the reference's exact association order:
// ((lps + d) + ((v0 - m0) - L0)) + ((v1 - m1) - L1)
__device__ __forceinline__ float post_val(float lpsb, float d,
                                          float v0, float mm0, float ll0,
                                          float v1, float mm1, float ll1) {
    return ((lpsb + d) + ((v0 - mm0) - ll0)) + ((v1 - mm1) - ll1);
}

// ---------- kernel 1: scaled tables = prior / 0.7 (true IEEE divide) ----------
__global__ void scale_kernel(const float* __restrict__ p0,
                             const float* __restrict__ p1,
                             float* __restrict__ sc) {
    const int NF4 = (KDIM * KDIM) / 4;
    int i = blockIdx.x * blockDim.x + threadIdx.x;
    float4 v;
    if (i < NF4) v = ((const float4*)p0)[i];
    else         v = ((const float4*)p1)[i - NF4];
    v.x = v.x / 0.7f; v.y = v.y / 0.7f; v.z = v.z / 0.7f; v.w = v.w / 0.7f;
    ((float4*)sc)[i] = v;
}

// ---------- kernel 2: per-row max + log-sum-exp of the scaled rows ----------
__global__ void rowstat_kernel(const float* __restrict__ sc,
                               float* __restrict__ mArr,
                               float* __restrict__ lArr) {
    __shared__ float red[4];
    __shared__ float bm;
    const int r = blockIdx.x;
    const float* row = sc + (size_t)r * KDIM;
    const int tid = threadIdx.x;
    const int lane = tid & 63, wv = tid >> 6;

    float4 a = ((const float4*)row)[tid];
    float4 b = ((const float4*)row)[tid + 256];
    float m = fmaxf(fmaxf(fmaxf(a.x, a.y), fmaxf(a.z, a.w)),
                    fmaxf(fmaxf(b.x, b.y), fmaxf(b.z, b.w)));
    for (int s = 32; s; s >>= 1) m = fmaxf(m, __shfl_xor(m, s));
    if (lane == 0) red[wv] = m;
    __syncthreads();
    if (tid == 0) bm = fmaxf(fmaxf(red[0], red[1]), fmaxf(red[2], red[3]));
    __syncthreads();
    const float mm = bm;

    float s = expf(a.x - mm);
    s += expf(a.y - mm); s += expf(a.z - mm); s += expf(a.w - mm);
    s += expf(b.x - mm); s += expf(b.y - mm); s += expf(b.z - mm); s += expf(b.w - mm);
    for (int sh = 32; sh; sh >>= 1) s += __shfl_xor(s, sh);
    __syncthreads();
    if (lane == 0) red[wv] = s;
    __syncthreads();
    if (tid == 0) {
        float S = ((red[0] + red[1]) + red[2]) + red[3];
        mArr[r] = mm;
        lArr[r] = logf(S);
    }
}

// full 64-lane bitonic sort: best (value desc, idx asc) ends in lane 0
__device__ __forceinline__ void bitonic64(float& v, int& i, int lane) {
    for (int k = 2; k <= 64; k <<= 1) {
        for (int j = k >> 1; j > 0; j >>= 1) {
            float ov = __shfl_xor(v, j);
            int   oi = __shfl_xor(i, j);
            bool lower = (lane & j) == 0;
            bool up    = (lane & k) == 0;
            bool iwin  = (v > ov) || (v == ov && i < oi);
            bool take  = (lower == up) ? !iwin : iwin;
            if (take) { v = ov; i = oi; }
        }
    }
}

// wave0 only: exact top-16 of cv/ci[0..C) with (value desc, idx asc);
// after return lane r (r<16) holds rank-r in (myv,myi). Requires C >= 16.
__device__ __forceinline__ void wave_top16(int C, float* cv, int* ci, int lane,
                                           float& myv, int& myi) {
    myv = -INFINITY; myi = 0x7FFFFFFF;
    if (C <= 64) {
        float v = (lane < C) ? cv[lane] : -INFINITY;
        int   i = (lane < C) ? ci[lane] : 0x7FFFFFFF;
        bitonic64(v, i, lane);
        myv = v; myi = i;
    } else {
        for (int rk = 0; rk < BEAMS; ++rk) {
            float bv = -INFINITY; int bi = 0x7FFFFFFF, bj = -1;
            for (int j = lane; j < C; j += 64) {
                float v = cv[j]; int ii = ci[j];
                if (v > bv || (v == bv && ii < bi)) { bv = v; bi = ii; bj = j; }
            }
            for (int s = 32; s; s >>= 1) {
                float ov = __shfl_xor(bv, s);
                int   oi = __shfl_xor(bi, s);
                int   oj = __shfl_xor(bj, s);
                if (ov > bv || (ov == bv && oi < bi)) { bv = ov; bi = oi; bj = oj; }
            }
            if (lane == rk) { myv = bv; myi = bi; }
            if (lane == 0) cv[bj] = -INFINITY;   // wave-internal LDS order is in-issue-order
        }
    }
}

// monotone-epoch centralized grid barrier (all NWG WGs co-resident)
__device__ __forceinline__ void grid_barrier(unsigned* cnt, unsigned target) {
    __syncthreads();
    if (threadIdx.x == 0) {
        __threadfence();   // agent-scope release of this WG's global writes
        __hip_atomic_fetch_add(cnt, 1u, __ATOMIC_ACQ_REL, __HIP_MEMORY_SCOPE_AGENT);
        while (__hip_atomic_load(cnt, __ATOMIC_ACQUIRE, __HIP_MEMORY_SCOPE_AGENT) < target) {
            __builtin_amdgcn_s_sleep(2);
        }
    }
    __syncthreads();
}

// ---------- kernel 3: 64-workgroup beam search, 1 grid barrier per step ----------
__global__ __launch_bounds__(256, 1) void beam_kernel(
    const float* __restrict__ sc,        // [2*2048][2048] scaled tables
    const float* __restrict__ mArr,      // [4096]
    const float* __restrict__ lArr,      // [4096]
    const float* __restrict__ ll_data,   // [1024][4096]
    const int*   __restrict__ ll_coords, // [1024][2][4096]
    const int*   __restrict__ x0i,
    const int*   __restrict__ x1i,
    float* __restrict__ out,
    unsigned* __restrict__ barCnt,
    float* __restrict__ gv,              // [2][NWG*16] candidate values
    int*   __restrict__ gi)              // [2][NWG*16] candidate flat indices
{
    __shared__ int   sx0[BEAMS], sx1[BEAMS];
    __shared__ float slps[BEAMS];
    __shared__ float wred[4];
    __shared__ float stau;
    __shared__ int   scnt;
    __shared__ float cand_v[LCAP];
    __shared__ int   cand_i[LCAP];
    __shared__ float res_v[BEAMS];
    __shared__ int   res_i[BEAMS];

    const int tid  = threadIdx.x;
    const int lane = tid & 63;
    const int wv   = tid >> 6;
    const int wg   = blockIdx.x;
    const int b    = wg >> 2;            // beam of this WG
    const int nbase = (wg & 3) * CHUNK;  // n-range start
    const float* sc1 = sc + (size_t)KDIM * KDIM;

    if (tid < BEAMS) { sx0[tid] = x0i[tid]; sx1[tid] = x1i[tid]; slps[tid] = 0.0f; }
    __syncthreads();

#pragma unroll 1
    for (int t = 0; t < TSTEPS; ++t) {
        const float* dp  = ll_data + (size_t)t * NNZ;
        const int*   cp  = ll_coords + (size_t)t * 2 * NNZ;
        const int    buf = t & 1;
        float* gvb = gv + buf * (NWG * BEAMS);
        int*   gib = gi + buf * (NWG * BEAMS);

        // ---- eval: 4 posteriors per thread, gathered straight from L2/L3 ----
        const int   r0i = sx0[b], r1i = sx1[b];
        const float* r0 = sc  + (size_t)r0i * KDIM;
        const float* r1 = sc1 + (size_t)r1i * KDIM;
        const float mm0 = mArr[r0i],        ll0 = lArr[r0i];
        const float mm1 = mArr[KDIM + r1i], ll1 = lArr[KDIM + r1i];
        const float lpsb = slps[b];
        const int n0 = nbase + tid * 4;
        float4 d4 = *(const float4*)(dp + n0);
        int4   a4 = *(const int4*)(cp + n0);
        int4   b4 = *(const int4*)(cp + NNZ + n0);
        float va0 = r0[a4.x], va1 = r0[a4.y], va2 = r0[a4.z], va3 = r0[a4.w];
        float vb0 = r1[b4.x], vb1 = r1[b4.y], vb2 = r1[b4.z], vb3 = r1[b4.w];
        float p0 = post_val(lpsb, d4.x, va0, mm0, ll0, vb0, mm1, ll1);
        float p1 = post_val(lpsb, d4.y, va1, mm0, ll0, vb1, mm1, ll1);
        float p2 = post_val(lpsb, d4.z, va2, mm0, ll0, vb2, mm1, ll1);
        float p3 = post_val(lpsb, d4.w, va3, mm0, ll0, vb3, mm1, ll1);

        if (tid == 0) scnt = 0;
        // wave-level 16th-distinct-max of per-thread maxima -> lower bound tau
        float best = fmaxf(fmaxf(p0, p1), fmaxf(p2, p3));
        {
            float cur = best, wth = -INFINITY;
#pragma unroll 1
            for (int k = 0; k < 16; ++k) {
                float wm = cur;
                for (int s = 32; s; s >>= 1) wm = fmaxf(wm, __shfl_xor(wm, s));
                wth = wm;
                cur = (cur == wm) ? -INFINITY : cur;
            }
            if (lane == 0) wred[wv] = wth;
        }
        __syncthreads();
        const float tau = fmaxf(fmaxf(wred[0], wred[1]), fmaxf(wred[2], wred[3]));

        if (p0 >= tau) { int pos = atomicAdd(&scnt, 1); cand_v[pos] = p0; cand_i[pos] = (b << 12) | (n0 + 0); }
        if (p1 >= tau) { int pos = atomicAdd(&scnt, 1); cand_v[pos] = p1; cand_i[pos] = (b << 12) | (n0 + 1); }
        if (p2 >= tau) { int pos = atomicAdd(&scnt, 1); cand_v[pos] = p2; cand_i[pos] = (b << 12) | (n0 + 2); }
        if (p3 >= tau) { int pos = atomicAdd(&scnt, 1); cand_v[pos] = p3; cand_i[pos] = (b << 12) | (n0 + 3); }
        __syncthreads();

        // local exact sorted top-16 -> global list slot [wg]
        if (wv == 0) {
            float myv; int myi;
            wave_top16(scnt, cand_v, cand_i, lane, myv, myi);
            if (lane < BEAMS) {
                gvb[wg * BEAMS + lane] = myv;
                gib[wg * BEAMS + lane] = myi;
            }
        }

        grid_barrier(barCnt, (unsigned)(t + 1) * NWG);

        // ---- redundant merge of 64 sorted lists (identical in every WG) ----
        if (tid == 0) scnt = 0;
        if (wv == 0) {
            float cur = gvb[lane * BEAMS];      // head of list `lane`
            float th = -INFINITY;
#pragma unroll 1
            for (int k = 0; k < 16; ++k) {
                float wm = cur;
                for (int s = 32; s; s >>= 1) wm = fmaxf(wm, __shfl_xor(wm, s));
                th = wm;
                cur = (cur == wm) ? -INFINITY : cur;
            }
            if (lane == 0) stau = th;
        }
        __syncthreads();
        const float taug = stau;
        for (int j = tid; j < NWG * BEAMS; j += 256) {
            float v = gvb[j];
            if (v >= taug) { int pos = atomicAdd(&scnt, 1); cand_v[pos] = v; cand_i[pos] = gib[j]; }
        }
        __syncthreads();
        if (wv == 0) {
            float myv; int myi;
            wave_top16(scnt, cand_v, cand_i, lane, myv, myi);
            if (lane < BEAMS) { res_v[lane] = myv; res_i[lane] = myi; }
        }
        __syncthreads();

        // state update (identical everywhere); WG0 writes outputs
        if (tid < BEAMS) {
            float v = res_v[tid]; int idx = res_i[tid];
            int n = idx & (NNZ - 1);
            int tok0 = cp[n];
            int tok1 = cp[NNZ + n];
            sx0[tid] = tok0; sx1[tid] = tok1; slps[tid] = v;
            if (wg == 0) {
                out[BEAMS + (size_t)t * BEAMS + tid] = (float)tok0;
                out[BEAMS + (size_t)TSTEPS * BEAMS + (size_t)t * BEAMS + tid] = (float)tok1;
                if (t == TSTEPS - 1) out[tid] = v;
            }
        }
        __syncthreads();
    }
}

extern "C" void kernel_launch(void* const* d_in, const int* in_sizes, int n_in,
                              void* d_out, int out_size, void* d_ws, size_t ws_size,
                              hipStream_t stream) {
    const float* p0        = (const float*)d_in[0];
    const float* p1        = (const float*)d_in[1];
    const float* ll_data   = (const float*)d_in[2];
    const int*   ll_coords = (const int*)d_in[3];
    const int*   x0i       = (const int*)d_in[4];
    const int*   x1i       = (const int*)d_in[5];
    float* outp = (float*)d_out;

    float* sc   = (float*)d_ws;                       // 32 MB scaled tables
    float* mArr = sc + (size_t)2 * KDIM * KDIM;       // 4096
    float* lArr = mArr + 2 * KDIM;                    // 4096
    float* gv   = lArr + 2 * KDIM;                    // 2*NWG*16 values
    int*   gi   = (int*)(gv + 2 * NWG * BEAMS);       // 2*NWG*16 indices
    unsigned* barCnt = (unsigned*)(gi + 2 * NWG * BEAMS);

    hipMemsetAsync(barCnt, 0, 64, stream);            // epoch counter = 0
    scale_kernel<<<(2 * KDIM * KDIM / 4) / 256, 256, 0, stream>>>(p0, p1, sc);
    rowstat_kernel<<<2 * KDIM, 256, 0, stream>>>(sc, mArr, lArr);
    beam_kernel<<<NWG, 256, 0, stream>>>(sc, mArr, lArr, ll_data, ll_coords,
                                         x0i, x1i, outp, barCnt, gv, gi);
}